// Round 14
// baseline (240.423 us; speedup 1.0000x reference)
//
#include <hip/hip_runtime.h>
#include <hip/hip_fp16.h>

// ---------------------------------------------------------------------------
// VGAE encoder: two GCN propagations + dense transforms.
// Transform-first: t = x@W1, h = relu(agg(t)+b1), g = h@[Wmu|Wlv],
// [mu|lv] = agg(g)+bias  (agg commutes with the right-multiply).
// agg is MONOLITHIC row-gather (256B fp16 rows, 2 cache lines/edge):
//  - column-chunked variants die on L1 line-request rate (32B/row-request)
//  - 64-col slab split (12.8MB) barely moves L2 hit rate; this form is the
//    empirical floor (~2.5-3.2 TB/s L2-miss-path service, VALU ~50%/SIMD).
// CSR build: FIXED-CAPACITY buckets (CAP=8192 >> mean 4096), no global
// prefix scan. Partition LDS-SORTS its 8192 edges so the global pair writes
// are lane-sequential within bucket runs (line-dense; the unsorted scatter
// touched ~60 lines per wave-instruction).
// ---------------------------------------------------------------------------

using half8 = __attribute__((ext_vector_type(8))) _Float16;
using f32x4 = __attribute__((ext_vector_type(4))) float;
using f32x2 = __attribute__((ext_vector_type(2))) float;

constexpr int CAP = 8192;   // per-bucket edge capacity (mean 4096, +64 sigma)
constexpr int PB  = 8192;   // edges per partition block

// Fused setup: block 0 zeroes bcnt + detects int64 vs int32 edge_index
// (odd int32 words all zero => int64). Blocks 1..16 pack the two weight
// matrices into fp16 MFMA B-fragment order:
// b_frag for (nt,kt) at lane l holds B[k][c], k=kt*32+(l>>4)*8+e,
// c=nt*16+(l&15). blocks 1..8 -> W1 (ld 128); 9..16 -> [Wmu|Wlv] (ld 64).
__global__ void setup_kernel(const int* __restrict__ ei, int* __restrict__ mode,
                             int* __restrict__ bcnt, int K,
                             const float* __restrict__ W1,
                             const float* __restrict__ Wmu,
                             const float* __restrict__ Wlv,
                             __half* __restrict__ dst1,
                             __half* __restrict__ dst2) {
    if (blockIdx.x == 0) {
        int tid = threadIdx.x;
        for (int i = tid; i < K; i += 256) bcnt[i] = 0;
        if (tid < 64) {
            int any = 0;
            for (int k = tid; k < 1024; k += 64) any |= ei[2 * k + 1];
            unsigned long long b = __ballot(any != 0);
            if (tid == 0) *mode = (b == 0ull) ? 1 : 0;
        }
        return;
    }
    int blk = blockIdx.x - 1;
    int which = blk >> 3;
    int t = (blk & 7) * 256 + threadIdx.x;   // 0..2047
    int lane = t & 63;
    int fk = t >> 6;          // nt*4 + kt
    int kt = fk & 3, nt = fk >> 2;
    int k0 = kt * 32 + ((lane >> 4) << 3);
    int c = nt * 16 + (lane & 15);
    const float* W;
    __half* dst;
    int ldw, cc;
    if (which) {
        W = (c < 64) ? Wmu : Wlv;
        cc = c & 63;
        ldw = 64;
        dst = dst2;
    } else {
        W = W1;
        cc = c;
        ldw = 128;
        dst = dst1;
    }
    __half tmp[8];
#pragma unroll
    for (int e = 0; e < 8; ++e)
        tmp[e] = __float2half(W[(size_t)(k0 + e) * ldw + cc]);
    *(float4*)(dst + (size_t)t * 8) = *(float4*)tmp;
}

// Partition with LDS sort: pass A histograms buckets; reserve global runs
// (1 atomic per block,bucket); 512-entry LDS scan -> local run offsets;
// pass B re-reads ei (own slice, L2-hot) and scatters (pair,bucket) into
// LDS; write phase emits slots in order -> lane-sequential global writes.
__global__ __launch_bounds__(256) void partition_kernel(
    const int* __restrict__ ei, int E, int n, const int* __restrict__ mode,
    int* __restrict__ bcnt, unsigned* __restrict__ pairs) {
    __shared__ unsigned sh_pair[PB];          // 32 KB
    __shared__ unsigned short sh_b[PB];       // 16 KB
    __shared__ int hist[512];
    __shared__ int loff[512];
    __shared__ int gbase[512];
    __shared__ int cur[512];
    __shared__ int wtot[4];
    int t = threadIdx.x;
    for (int i = t; i < 512; i += 256) hist[i] = 0;
    __syncthreads();
    int m = *mode;
    int e0 = blockIdx.x * PB;
    // pass A: bucket histogram
    for (int k = 0; k < PB / 256; ++k) {
        int e = e0 + k * 256 + t;
        if (e < E) {
            int s = m ? ei[2 * e] : ei[e];
            int d = m ? ei[2 * (E + e)] : ei[E + e];
            if ((unsigned)d < (unsigned)n && (unsigned)s < (unsigned)n)
                atomicAdd(&hist[d >> 8], 1);
        }
    }
    __syncthreads();
    // 512-entry exclusive scan with 256 threads (2 entries/thread) + reserve
    {
        int lane = t & 63, wv = t >> 6;
        int v0 = hist[2 * t], v1 = hist[2 * t + 1];
        int ps = v0 + v1;
        int incl = ps;
#pragma unroll
        for (int off = 1; off < 64; off <<= 1) {
            int u = __shfl_up(incl, off, 64);
            if (lane >= off) incl += u;
        }
        if (lane == 63) wtot[wv] = incl;
        __syncthreads();
        int wo = 0;
        for (int w = 0; w < wv; ++w) wo += wtot[w];
        int ex = wo + incl - ps;
        loff[2 * t] = ex;
        loff[2 * t + 1] = ex + v0;
        cur[2 * t] = ex;
        cur[2 * t + 1] = ex + v0;
        gbase[2 * t]     = v0 ? atomicAdd(&bcnt[2 * t], v0) : 0;
        gbase[2 * t + 1] = v1 ? atomicAdd(&bcnt[2 * t + 1], v1) : 0;
    }
    __syncthreads();
    int tot = loff[511] + hist[511];
    // pass B: re-read, scatter into LDS
    for (int k = 0; k < PB / 256; ++k) {
        int e = e0 + k * 256 + t;
        if (e < E) {
            int s = m ? ei[2 * e] : ei[e];
            int d = m ? ei[2 * (E + e)] : ei[E + e];
            if ((unsigned)d < (unsigned)n && (unsigned)s < (unsigned)n) {
                int b = d >> 8;
                int slot = atomicAdd(&cur[b], 1);
                sh_pair[slot] = (unsigned)s | ((unsigned)(d & 255) << 24);
                sh_b[slot] = (unsigned short)b;
            }
        }
    }
    __syncthreads();
    // write phase: consecutive slots -> consecutive global addresses per run
    for (int i = t; i < tot; i += 256) {
        int b = sh_b[i];
        pairs[(size_t)b * CAP + gbase[b] + (i - loff[b])] = sh_pair[i];
    }
}

// Fused CSR build, one block per bucket: LDS histogram of the bucket's
// packed pairs -> LDS scan -> per-node int2 bounds + dinv, then place
// csr_src via LDS cursors. All global windows L2-local.
__global__ __launch_bounds__(256) void build_kernel(
    const unsigned* __restrict__ pairs, const int* __restrict__ bcnt,
    int2* __restrict__ rowbe, float* __restrict__ dinv,
    int* __restrict__ csr_src, int n) {
    __shared__ int hist[256];
    __shared__ int wtot[4];
    int b = blockIdx.x;
    int cnt = bcnt[b];
    size_t gbase = (size_t)b * CAP;
    int tid = threadIdx.x, lane = tid & 63, wv = tid >> 6;
    hist[tid] = 0;
    __syncthreads();
    for (int i = tid; i < cnt; i += 256)
        atomicAdd(&hist[pairs[gbase + i] >> 24], 1);
    __syncthreads();
    int v = hist[tid];
    int incl = v;
#pragma unroll
    for (int off = 1; off < 64; off <<= 1) {
        int t = __shfl_up(incl, off, 64);
        if (lane >= off) incl += t;
    }
    if (lane == 63) wtot[wv] = incl;
    __syncthreads();
    int wo = 0;
    for (int w = 0; w < wv; ++w) wo += wtot[w];
    int ex = wo + incl - v;   // exclusive scan within bucket
    int node = (b << 8) + tid;
    if (node < n) {
        int beg = (int)gbase + ex;
        rowbe[node] = make_int2(beg, beg + v);
        dinv[node] = rsqrtf((float)(v + 1));   // +1 self-loop
    }
    __syncthreads();
    hist[tid] = ex;   // reuse as cursor
    __syncthreads();
    for (int i = tid; i < cnt; i += 256) {
        unsigned p = pairs[gbase + i];
        int pos = atomicAdd(&hist[p >> 24], 1);
        csr_src[gbase + pos] = (int)(p & 0x00FFFFFFu);
    }
}

// ---------------------------------------------------------------------------
// Monolithic row-gather aggregation (one wave per node, lane = half2 col).
// Wave-uniform src index via readfirstlane (scalar dinv load), 8-deep
// unroll for MLP. out = di*(di*T[i] + sum_e dinv[s]*T[s]) + bias.
// Bias: lane<32 -> biasa[2*lane..], lane>=32 -> biasb[(2*lane)&63..].
// MODE 0: relu, fp16 row-major out (h). MODE 1: f32 split slabs (mu | lv).
// ---------------------------------------------------------------------------
template <int MODE>
__global__ __launch_bounds__(256) void agg_row_kernel(
    const __half* __restrict__ T, const float* __restrict__ dinv,
    const int2* __restrict__ rowbe, const int* __restrict__ csr_src,
    const float* __restrict__ biasa, const float* __restrict__ biasb,
    void* __restrict__ outa, void* __restrict__ outb, int n) {
    int wave = (int)((blockIdx.x * blockDim.x + threadIdx.x) >> 6);
    int lane = threadIdx.x & 63;
    if (wave >= n) return;
    const __half2* x2 = (const __half2*)T;
    float di = dinv[wave];
    float2 xf = __half22float2(x2[((size_t)wave << 6) + lane]);
    float ax = 0.f, ay = 0.f;
    int2 be = rowbe[wave];
    int e = be.x, end = be.y;
    for (; e + 8 <= end; e += 8) {
        int s[8];
        float w[8];
        float2 u[8];
#pragma unroll
        for (int k = 0; k < 8; ++k)
            s[k] = __builtin_amdgcn_readfirstlane(csr_src[e + k]);
#pragma unroll
        for (int k = 0; k < 8; ++k) w[k] = dinv[s[k]];
#pragma unroll
        for (int k = 0; k < 8; ++k)
            u[k] = __half22float2(x2[((size_t)s[k] << 6) + lane]);
#pragma unroll
        for (int k = 0; k < 8; ++k) {
            ax += w[k] * u[k].x;
            ay += w[k] * u[k].y;
        }
    }
    for (; e < end; ++e) {
        int s = __builtin_amdgcn_readfirstlane(csr_src[e]);
        float w = dinv[s];
        float2 u = __half22float2(x2[((size_t)s << 6) + lane]);
        ax += w * u.x;
        ay += w * u.y;
    }
    const float* bp = (lane < 32) ? biasa : biasb;
    float2 bv = *(const float2*)(bp + ((2 * lane) & 63));
    float vx = di * (di * xf.x + ax) + bv.x;
    float vy = di * (di * xf.y + ay) + bv.y;
    if (MODE == 0) {
        vx = fmaxf(vx, 0.f);
        vy = fmaxf(vy, 0.f);
        __half2 hv = __floats2half2_rn(vx, vy);
        unsigned int bits;
        __builtin_memcpy(&bits, &hv, 4);
        unsigned int* o = (unsigned int*)outa;
        __builtin_nontemporal_store(bits, o + ((size_t)wave << 6) + lane);
    } else {
        // cols 2*lane, 2*lane+1: lane<32 -> mu slab, lane>=32 -> lv slab
        float* o = (lane < 32) ? (float*)outa : (float*)outb;
        int cc = (2 * lane) & 63;
        f32x2 v = {vx, vy};
        __builtin_nontemporal_store(v, (f32x2*)(o + (size_t)wave * 64 + cc));
    }
}

// ---------------------------------------------------------------------------
// Pure MFMA GEMM (no bias/relu): A [n x 128] (f32 or fp16 row-major) @
// packed Wp -> fp16 row-major out. 4 waves/block, 16-row strip per wave.
// A-frag: lane holds row (lane&15), k = kt*32+(lane>>4)*8+e
// C-frag: col = lane&15, row = (lane>>4)*4 + reg   (m89-verified)
// ---------------------------------------------------------------------------
template <typename AT>
__global__ __launch_bounds__(256) void gemm_pure_kernel(
    const AT* __restrict__ A, const __half* __restrict__ Wp,
    __half* __restrict__ outh, int n) {
    int lane = threadIdx.x & 63;
    int wv = threadIdx.x >> 6;
    int m0 = (blockIdx.x * 4 + wv) * 16;
    if (m0 >= n) return;
    int row_a = m0 + (lane & 15);
    if (row_a >= n) row_a = n - 1;              // clamp; stores guarded
    half8 afr[4];
    if constexpr (sizeof(AT) == 4) {
        const float4* Arow = (const float4*)(A + (size_t)row_a * 128);
#pragma unroll
        for (int kt = 0; kt < 4; ++kt) {
            float4 lo = Arow[kt * 8 + ((lane >> 4) << 1)];
            float4 hi = Arow[kt * 8 + ((lane >> 4) << 1) + 1];
            half8 h;
            h[0] = (_Float16)lo.x; h[1] = (_Float16)lo.y;
            h[2] = (_Float16)lo.z; h[3] = (_Float16)lo.w;
            h[4] = (_Float16)hi.x; h[5] = (_Float16)hi.y;
            h[6] = (_Float16)hi.z; h[7] = (_Float16)hi.w;
            afr[kt] = h;
        }
    } else {
        const half8* Arow = (const half8*)(A + (size_t)row_a * 128);
#pragma unroll
        for (int kt = 0; kt < 4; ++kt) afr[kt] = Arow[kt * 4 + (lane >> 4)];
    }

    const half8* Wf = (const half8*)Wp;
    int colw = lane & 15;
    int rbase = m0 + ((lane >> 4) << 2);

#pragma unroll
    for (int nt = 0; nt < 8; ++nt) {
        f32x4 acc = {0.f, 0.f, 0.f, 0.f};
#pragma unroll
        for (int kt = 0; kt < 4; ++kt)
            acc = __builtin_amdgcn_mfma_f32_16x16x32_f16(
                afr[kt], Wf[(nt * 4 + kt) * 64 + lane], acc, 0, 0, 0);
        int c = nt * 16 + colw;
#pragma unroll
        for (int e = 0; e < 4; ++e) {
            int r = rbase + e;
            if (r < n) outh[(size_t)r * 128 + c] = __float2half(acc[e]);
        }
    }
}

extern "C" void kernel_launch(void* const* d_in, const int* in_sizes, int n_in,
                              void* d_out, int out_size, void* d_ws, size_t ws_size,
                              hipStream_t stream) {
    const float* x   = (const float*)d_in[0];
    const int*   ei  = (const int*)d_in[1];
    const float* W1  = (const float*)d_in[2];
    const float* b1  = (const float*)d_in[3];
    const float* Wmu = (const float*)d_in[4];
    const float* bmu = (const float*)d_in[5];
    const float* Wlv = (const float*)d_in[6];
    const float* blv = (const float*)d_in[7];
    float* out = (float*)d_out;

    const int n = in_sizes[0] / 128;   // 100000
    const int E = in_sizes[1] / 2;     // 1600000
    const int K = (n + 255) >> 8;      // dst buckets (391, <=512)

    char* ws = (char*)d_ws;
    size_t off = 0;
    auto alloc = [&](size_t bytes) -> void* {
        void* p = ws + off;
        off += (bytes + 255) & ~(size_t)255;
        return p;
    };
    int*      mode    = (int*)alloc(256);
    int*      bcnt    = (int*)alloc((size_t)K * 4);
    int2*     rowbe   = (int2*)alloc((size_t)n * 8);
    float*    dinv    = (float*)alloc((size_t)n * 4);
    int*      csr_src = (int*)alloc((size_t)K * CAP * 4);
    unsigned* pairs   = (unsigned*)alloc((size_t)K * CAP * 4);
    __half*   bufT    = (__half*)alloc((size_t)n * 128 * 2);  // t, then g
    __half*   bufH    = (__half*)alloc((size_t)n * 128 * 2);  // h
    __half*   W1p     = (__half*)alloc(128 * 128 * 2);        // packed W1
    __half*   W2p     = (__half*)alloc(128 * 128 * 2);        // packed [Wmu|Wlv]

    // setup: zero bcnt, detect index width, pack both weight matrices
    setup_kernel<<<17, 256, 0, stream>>>(ei, mode, bcnt, K,
                                         W1, Wmu, Wlv, W1p, W2p);

    int pb = (E + PB - 1) / PB;
    partition_kernel<<<pb, 256, 0, stream>>>(ei, E, n, mode, bcnt, pairs);
    build_kernel<<<K, 256, 0, stream>>>(pairs, bcnt, rowbe, dinv, csr_src, n);

    int gb = (n + 63) / 64;        // MFMA gemm blocks
    int ab = (n + 3) / 4;          // agg: 4 waves/block, 1 wave/node

    // t = x @ W1  (f32 A -> fp16 row-major)
    gemm_pure_kernel<float><<<gb, 256, 0, stream>>>(x, W1p, bufT, n);
    // h = relu(agg(t) + b1)
    agg_row_kernel<0><<<ab, 256, 0, stream>>>(bufT, dinv, rowbe, csr_src,
                                              b1, b1 + 64, bufH, nullptr, n);
    // g = h @ [Wmu|Wlv]
    gemm_pure_kernel<__half><<<gb, 256, 0, stream>>>(bufH, W2p, bufT, n);
    // mu / logvar = agg(g) + bias  (f32 slabs)
    agg_row_kernel<1><<<ab, 256, 0, stream>>>(bufT, dinv, rowbe, csr_src,
                                              bmu, blv, out,
                                              out + (size_t)n * 64, n);
}